// Round 2
// baseline (470.303 us; speedup 1.0000x reference)
//
#include <hip/hip_runtime.h>

#define NGRID 8192
#define NLAYER 24
#define NPERIODS 50
#define NOBS 4096
#define NC 200
#define PP 64            // periods padded to 64 (r_pad, c_pred layout)
#define NSPLIT 16        // g-splits across blockIdx.y in K2
#define WPB 8            // waves per block in K2
#define GC 64            // g per wave = NGRID/(NSPLIT*WPB)
#define KG 16            // g subtile staged in LDS per wave
#define LDSTR 20         // KG+4: b128 conflict-free stride
#define NBINS 1024
#define OTILE 64
#define VREF 3.0f

// ---------------- K0: zero the atomic bins ----------------
__global__ void k0_zero(float* __restrict__ bins) {
    bins[threadIdx.x] = 0.f;
}

// ---------------- K1: r_pad[g][p] = 1/(0.92 * sum_l w[p][l]*Vs[g][l]) ----------------
__global__ __launch_bounds__(256) void k1_rpad(const float* __restrict__ Vs,
                                               const float* __restrict__ thick,
                                               const float* __restrict__ periods,
                                               float* __restrict__ r_pad) {
    __shared__ float w_sh[NLAYER][NPERIODS];   // transposed: reads are conflict-free
    __shared__ float z_sh[NLAYER];
    int tid = threadIdx.x;
    if (tid < NLAYER) {
        float c = 0.f;
        for (int i = 0; i <= tid; ++i) c += thick[i];
        z_sh[tid] = c - 0.5f * thick[tid];
    }
    __syncthreads();
    if (tid < NPERIODS) {
        float ds = (VREF / 3.0f) * periods[tid];
        float tmp[NLAYER];
        float s = 0.f;
        #pragma unroll
        for (int l = 0; l < NLAYER; ++l) {
            float v = expf(-z_sh[l] / ds) * thick[l];
            tmp[l] = v; s += v;
        }
        float inv = 1.f / s;
        #pragma unroll
        for (int l = 0; l < NLAYER; ++l) w_sh[l][tid] = tmp[l] * inv;
    }
    __syncthreads();
    int idx = blockIdx.x * 256 + tid;          // idx = g*64 + p  (lanes share g -> broadcast Vs)
    int g = idx >> 6, p = idx & 63;
    float r = 0.f;
    if (p < NPERIODS) {
        const float4* vp = (const float4*)(Vs + (size_t)g * NLAYER);
        float s = 0.f;
        #pragma unroll
        for (int q = 0; q < NLAYER / 4; ++q) {
            float4 t = vp[q];
            s = fmaf(w_sh[4*q+0][p], t.x, s);
            s = fmaf(w_sh[4*q+1][p], t.y, s);
            s = fmaf(w_sh[4*q+2][p], t.z, s);
            s = fmaf(w_sh[4*q+3][p], t.w, s);
        }
        r = 1.0f / (0.92f * s);
    }
    r_pad[idx] = r;                            // fully coalesced, zero-padded p>=50
}

// ---------------- K2: partial[s][o][p] = sum_{g in split s} A[o][g]*r[g][p] ----------------
// lane <-> obs (64 obs/wave), 50 fp32 accumulators/lane in VGPRs.
// r[g][p] wave-uniform -> s_load; A staged via wave-PRIVATE LDS tile (no barriers
// in the main loop). 8 waves/block, NSPLIT=16 -> 8192 waves = 32 waves/CU.
__global__ __launch_bounds__(512, 8) void k2_gemm(const float* __restrict__ A,
                                                  const float* __restrict__ r_pad,
                                                  float* __restrict__ partial) {
    __shared__ float lds[WPB * OTILE * LDSTR];             // 40 KB -> 4 blocks/CU
    int tid  = threadIdx.x;
    int lane = tid & 63;
    int wv   = __builtin_amdgcn_readfirstlane(tid >> 6);   // uniform -> s_load of r
    int o_base = blockIdx.x * OTILE;
    int split  = blockIdx.y;
    float* Aw = lds + wv * (OTILE * LDSTR);

    float acc[NPERIODS];
    #pragma unroll
    for (int p = 0; p < NPERIODS; ++p) acc[p] = 0.f;

    int g_wave = (split * WPB + wv) * GC;

    #pragma unroll 1
    for (int kt = 0; kt < GC / KG; ++kt) {                 // 4 subtiles of 16 g
        int g0 = g_wave + kt * KG;
        // stage 64 obs x 16 g: 4 float4 per lane; 4 lanes cover 64B per obs-row
        #pragma unroll
        for (int s = 0; s < 4; ++s) {
            int f   = s * 64 + lane;
            int row = f >> 2;
            int c4  = (f & 3) * 4;
            float4 t = *(const float4*)(A + (size_t)(o_base + row) * NGRID + g0 + c4);
            *(float4*)(Aw + row * LDSTR + c4) = t;
        }
        // NO barrier: tile is wave-private, compiler inserts per-wave waitcnts
        #pragma unroll 1
        for (int gg = 0; gg < KG; gg += 4) {
            float4 a4 = *(const float4*)(Aw + lane * LDSTR + gg);
            const float* rr = r_pad + (size_t)(g0 + gg) * PP;
            #pragma unroll
            for (int j = 0; j < 4; ++j) {
                float aj = (j == 0) ? a4.x : (j == 1) ? a4.y : (j == 2) ? a4.z : a4.w;
                const float* rj = rr + j * PP;             // uniform address -> s_load
                #pragma unroll
                for (int p = 0; p < NPERIODS; ++p) acc[p] = fmaf(aj, rj[p], acc[p]);
            }
        }
    }

    // epilogue: cross-wave reduce (8 waves, same 64 obs) in 4 phases of 16 p
    float* outp = partial + (size_t)split * (NOBS * NPERIODS) + (size_t)o_base * NPERIODS;
    #pragma unroll 1
    for (int h = 0; h < 4; ++h) {
        __syncthreads();
        float* rw = lds + wv * (OTILE * 17);               // stride 17 -> conflict-free
        #pragma unroll
        for (int q = 0; q < 16; ++q) {
            int p = h * 16 + q;
            rw[lane * 17 + q] = (p < NPERIODS) ? acc[p] : 0.f;
        }
        __syncthreads();
        for (int e = tid; e < OTILE * 16; e += 512) {
            int oo = e >> 4, q = e & 15;
            int p  = h * 16 + q;
            if (p < NPERIODS) {
                float v = 0.f;
                #pragma unroll
                for (int w2 = 0; w2 < WPB; ++w2) v += lds[w2 * (OTILE * 17) + oo * 17 + q];
                outp[oo * NPERIODS + p] = v;
            }
        }
    }
}

// ---------------- K2b: c_pred[o*64+p] = 1 / sum_s partial[s][o][p]  (coalesced) ----------------
__global__ __launch_bounds__(256) void k2b_reduce(const float* __restrict__ partial,
                                                  float* __restrict__ cpred) {
    int idx = blockIdx.x * 256 + threadIdx.x;
    int o = idx >> 6, p = idx & 63;
    float v = 0.f;
    if (p < NPERIODS) {
        float s = 0.f;
        #pragma unroll
        for (int sp = 0; sp < NSPLIT; ++sp)
            s += partial[(size_t)sp * (NOBS * NPERIODS) + (size_t)o * NPERIODS + p];
        v = 1.0f / s;
    }
    cpred[idx] = v;
}

// ---------------- K3: block per obs; per period-row: max, searchsorted, interp ----------------
__global__ __launch_bounds__(256) void k3_main(const float* __restrict__ energy,
                                               const float* __restrict__ c_axis,
                                               const float* __restrict__ cpred,
                                               float* __restrict__ bins) {
    __shared__ float csh[NC];
    __shared__ float red[4];
    int tid  = threadIdx.x;
    int lane = tid & 63;
    int wv   = tid >> 6;
    int o    = blockIdx.x;

    if (tid < NC) csh[tid] = c_axis[(size_t)o * NC + tid];
    __syncthreads();

    float4 ca = make_float4(0.f, 0.f, 0.f, 0.f);
    if (lane < NC / 4) ca = *(const float4*)(csh + 4 * lane);   // held in regs across rows

    float local = 0.f;
    for (int p = wv; p < NPERIODS; p += 4) {
        float cp = cpred[(size_t)o * PP + p];                   // broadcast load
        const float* erow = energy + ((size_t)o * NPERIODS + p) * NC;
        float mx = -1e30f, cnt = 0.f;
        if (lane < NC / 4) {
            float4 e = *(const float4*)(erow + 4 * lane);
            mx  = fmaxf(fmaxf(e.x, e.y), fmaxf(e.z, e.w));
            cnt = (ca.x < cp ? 1.f : 0.f) + (ca.y < cp ? 1.f : 0.f)
                + (ca.z < cp ? 1.f : 0.f) + (ca.w < cp ? 1.f : 0.f);
        }
        #pragma unroll
        for (int m = 32; m; m >>= 1) {
            cnt += __shfl_xor(cnt, m, 64);
            mx   = fmaxf(mx, __shfl_xor(mx, m, 64));
        }
        int idx = (int)cnt;                    // searchsorted 'left' = count(a < v)
        idx = idx < 1 ? 1 : (idx > NC - 1 ? NC - 1 : idx);
        float c0 = csh[idx - 1], c1 = csh[idx];                 // LDS broadcast
        float e0 = erow[idx - 1], e1 = erow[idx];               // L1 hit (line just read)
        float w  = (cp - c0) / (c1 - c0 + 1e-12f);
        float ei = fmaf(w, e1 - e0, e0);
        local += mx - ei;
    }
    if (lane == 0) red[wv] = local;
    __syncthreads();
    if (tid == 0)
        atomicAdd(&bins[blockIdx.x & (NBINS - 1)], red[0] + red[1] + red[2] + red[3]);
}

// ---------------- K4: final reduce of bins -> out ----------------
__global__ __launch_bounds__(256) void k4_final(const float* __restrict__ bins,
                                                float* __restrict__ out) {
    __shared__ float red[4];
    int tid = threadIdx.x;
    float s = 0.f;
    for (int i = tid; i < NBINS; i += 256) s += bins[i];
    #pragma unroll
    for (int m = 32; m; m >>= 1) s += __shfl_xor(s, m, 64);
    int lane = tid & 63, wv = tid >> 6;
    if (lane == 0) red[wv] = s;
    __syncthreads();
    if (tid == 0) out[0] = -(red[0] + red[1] + red[2] + red[3]);  // / SIGMA^2 == 1
}

extern "C" void kernel_launch(void* const* d_in, const int* in_sizes, int n_in,
                              void* d_out, int out_size, void* d_ws, size_t ws_size,
                              hipStream_t stream) {
    const float* Vs      = (const float*)d_in[0];
    const float* A       = (const float*)d_in[1];
    const float* energy  = (const float*)d_in[2];
    const float* c_axis  = (const float*)d_in[3];
    const float* thick   = (const float*)d_in[4];
    const float* periods = (const float*)d_in[5];
    float* out = (float*)d_out;

    float* ws      = (float*)d_ws;
    float* r_pad   = ws;                                        // 2 MB
    float* partial = r_pad + (size_t)NGRID * PP;                // 16*4096*50*4 = 13.1 MB
    float* cpred   = partial + (size_t)NSPLIT * NOBS * NPERIODS;// 1 MB
    float* bins    = cpred + (size_t)NOBS * PP;                 // 4 KB

    hipLaunchKernelGGL(k0_zero, dim3(1), dim3(NBINS), 0, stream, bins);
    hipLaunchKernelGGL(k1_rpad, dim3((NGRID * PP) / 256), dim3(256), 0, stream,
                       Vs, thick, periods, r_pad);
    hipLaunchKernelGGL(k2_gemm, dim3(NOBS / OTILE, NSPLIT), dim3(512), 0, stream,
                       A, r_pad, partial);
    hipLaunchKernelGGL(k2b_reduce, dim3((NOBS * PP) / 256), dim3(256), 0, stream,
                       partial, cpred);
    hipLaunchKernelGGL(k3_main, dim3(NOBS), dim3(256), 0, stream,
                       energy, c_axis, cpred, bins);
    hipLaunchKernelGGL(k4_final, dim3(1), dim3(256), 0, stream, bins, out);
}

// Round 3
// 389.638 us; speedup vs baseline: 1.2070x; 1.2070x over previous
//
#include <hip/hip_runtime.h>

#define NGRID 8192
#define NLAYER 24
#define NPERIODS 50
#define NOBS 4096
#define NC 200
#define PP 64            // periods padded to 64 (r_pad, c_pred layout)
#define NSPLIT 16        // g-splits across blockIdx.y in K2
#define WPB 4            // waves per block in K2
#define GC (NGRID / (NSPLIT * WPB))   // 128 g per wave
#define KG 32            // g subtile staged in LDS per wave
#define ASTR 36          // LDS stride: measured 0 bank conflicts in R1
#define NBINS 1024
#define OTILE 64
#define VREF 3.0f

// ---------------- K1: r_pad[g][p] = 1/(0.92 * sum_l w[p][l]*Vs[g][l]); block 0 zeroes bins ----------------
__global__ __launch_bounds__(256) void k1_rpad(const float* __restrict__ Vs,
                                               const float* __restrict__ thick,
                                               const float* __restrict__ periods,
                                               float* __restrict__ r_pad,
                                               float* __restrict__ bins) {
    __shared__ float w_sh[NLAYER][NPERIODS];   // transposed: reads are conflict-free
    __shared__ float z_sh[NLAYER];
    int tid = threadIdx.x;
    if (blockIdx.x == 0) {
        for (int i = tid; i < NBINS; i += 256) bins[i] = 0.f;
    }
    if (tid < NLAYER) {
        float c = 0.f;
        for (int i = 0; i <= tid; ++i) c += thick[i];
        z_sh[tid] = c - 0.5f * thick[tid];
    }
    __syncthreads();
    if (tid < NPERIODS) {
        float ds = (VREF / 3.0f) * periods[tid];
        float tmp[NLAYER];
        float s = 0.f;
        #pragma unroll
        for (int l = 0; l < NLAYER; ++l) {
            float v = expf(-z_sh[l] / ds) * thick[l];
            tmp[l] = v; s += v;
        }
        float inv = 1.f / s;
        #pragma unroll
        for (int l = 0; l < NLAYER; ++l) w_sh[l][tid] = tmp[l] * inv;
    }
    __syncthreads();
    int idx = blockIdx.x * 256 + tid;          // idx = g*64 + p  (lanes share g -> broadcast Vs)
    int g = idx >> 6, p = idx & 63;
    float r = 0.f;
    if (p < NPERIODS) {
        const float4* vp = (const float4*)(Vs + (size_t)g * NLAYER);
        float s = 0.f;
        #pragma unroll
        for (int q = 0; q < NLAYER / 4; ++q) {
            float4 t = vp[q];
            s = fmaf(w_sh[4*q+0][p], t.x, s);
            s = fmaf(w_sh[4*q+1][p], t.y, s);
            s = fmaf(w_sh[4*q+2][p], t.z, s);
            s = fmaf(w_sh[4*q+3][p], t.w, s);
        }
        r = 1.0f / (0.92f * s);
    }
    r_pad[idx] = r;                            // fully coalesced, zero-padded p>=50
}

// ---------------- K2: partial[s][o][p] = sum_{g in split s} A[o][g]*r[g][p] ----------------
// R1 structure (KG=32, stride 36: VGPR=56, 0 conflicts) with main-loop barriers
// REMOVED (wave-private LDS tile; per-wave lgkmcnt ordering is sufficient).
// Occupancy from grid shape: 1024 blocks = 4/CU (LDS-capped) = 16 waves/CU.
// NO min-waves launch bound — a VGPR cap below ~60 spills acc[50] (R2 lesson).
__global__ __launch_bounds__(256) void k2_gemm(const float* __restrict__ A,
                                               const float* __restrict__ r_pad,
                                               float* __restrict__ partial) {
    __shared__ float lds[WPB * OTILE * ASTR];              // 4*64*36*4 = 36864 B
    int tid  = threadIdx.x;
    int lane = tid & 63;
    int wv   = __builtin_amdgcn_readfirstlane(tid >> 6);   // uniform -> s_load of r
    int o_base = blockIdx.x * OTILE;
    int split  = blockIdx.y;
    float* Aw = lds + wv * (OTILE * ASTR);

    float acc[NPERIODS];
    #pragma unroll
    for (int p = 0; p < NPERIODS; ++p) acc[p] = 0.f;

    int g_wave = (split * WPB + wv) * GC;

    #pragma unroll 1
    for (int kt = 0; kt < GC / KG; ++kt) {                 // 4 subtiles of 32 g
        int g0 = g_wave + kt * KG;
        // stage 64 obs x 32 g: 8 float4 per lane; 8 lanes cover 128B per obs-row
        #pragma unroll
        for (int s = 0; s < 8; ++s) {
            int f   = s * 64 + lane;
            int row = f >> 3;
            int c4  = (f & 7) * 4;
            float4 t = *(const float4*)(A + (size_t)(o_base + row) * NGRID + g0 + c4);
            *(float4*)(Aw + row * ASTR + c4) = t;
        }
        // NO barrier: tile is wave-private
        #pragma unroll 1
        for (int gg = 0; gg < KG; gg += 4) {
            float4 a4 = *(const float4*)(Aw + lane * ASTR + gg);
            const float* rr = r_pad + (size_t)(g0 + gg) * PP;
            #pragma unroll
            for (int j = 0; j < 4; ++j) {
                float aj = (j == 0) ? a4.x : (j == 1) ? a4.y : (j == 2) ? a4.z : a4.w;
                const float* rj = rr + j * PP;             // uniform address -> s_load
                #pragma unroll
                for (int p = 0; p < NPERIODS; ++p) acc[p] = fmaf(aj, rj[p], acc[p]);
            }
        }
    }

    // epilogue: cross-wave reduce (4 waves, same 64 obs) in 4 phases of 16 p
    float* outp = partial + (size_t)split * (NOBS * NPERIODS) + (size_t)o_base * NPERIODS;
    #pragma unroll 1
    for (int h = 0; h < 4; ++h) {
        __syncthreads();
        float* rw = lds + wv * (OTILE * 17);               // stride 17 -> conflict-free
        #pragma unroll
        for (int q = 0; q < 16; ++q) {
            int p = h * 16 + q;
            rw[lane * 17 + q] = (p < NPERIODS) ? acc[p] : 0.f;
        }
        __syncthreads();
        for (int e = tid; e < OTILE * 16; e += 256) {
            int oo = e >> 4, q = e & 15;
            int p  = h * 16 + q;
            if (p < NPERIODS) {
                float v = 0.f;
                #pragma unroll
                for (int w2 = 0; w2 < WPB; ++w2) v += lds[w2 * (OTILE * 17) + oo * 17 + q];
                outp[oo * NPERIODS + p] = v;
            }
        }
    }
}

// ---------------- K2b: c_pred[o*64+p] = 1 / sum_s partial[s][o][p]  (coalesced) ----------------
__global__ __launch_bounds__(256) void k2b_reduce(const float* __restrict__ partial,
                                                  float* __restrict__ cpred) {
    int idx = blockIdx.x * 256 + threadIdx.x;
    int o = idx >> 6, p = idx & 63;
    float v = 0.f;
    if (p < NPERIODS) {
        float s = 0.f;
        #pragma unroll
        for (int sp = 0; sp < NSPLIT; ++sp)
            s += partial[(size_t)sp * (NOBS * NPERIODS) + (size_t)o * NPERIODS + p];
        v = 1.0f / s;
    }
    cpred[idx] = v;
}

// ---------------- K3: block per obs; ballot-based searchsorted, shuffle-based interp,
//                      2 period-rows in flight per wave ----------------
__global__ __launch_bounds__(256) void k3_main(const float* __restrict__ energy,
                                               const float* __restrict__ c_axis,
                                               const float* __restrict__ cpred,
                                               float* __restrict__ bins) {
    __shared__ float csh[NC];
    __shared__ float red[4];
    int tid  = threadIdx.x;
    int lane = tid & 63;
    int wv   = tid >> 6;
    int o    = blockIdx.x;

    if (tid < NC) csh[tid] = c_axis[(size_t)o * NC + tid];
    __syncthreads();

    bool act = lane < NC / 4;                  // 50 active lanes
    float4 ca = act ? *(const float4*)(csh + 4 * lane) : make_float4(9e30f, 9e30f, 9e30f, 9e30f);
    const float* ebase = energy + (size_t)o * NPERIODS * NC;
    float local = 0.f;

    for (int p0 = wv; p0 < NPERIODS; p0 += 8) {
        int p1 = p0 + 4;
        bool has1 = p1 < NPERIODS;
        int p1c = has1 ? p1 : p0;
        float cpA = cpred[(size_t)o * PP + p0];
        float cpB = cpred[(size_t)o * PP + p1c];
        const float* erA = ebase + (size_t)p0 * NC;
        const float* erB = ebase + (size_t)p1c * NC;
        float4 eA = act ? *(const float4*)(erA + 4 * lane) : make_float4(-1e30f, -1e30f, -1e30f, -1e30f);
        float4 eB = act ? *(const float4*)(erB + 4 * lane) : make_float4(-1e30f, -1e30f, -1e30f, -1e30f);

        // searchsorted 'left' = count(c_axis < cp) via ballot+popcount (no DS-pipe reduce)
        int cntA = __popcll(__ballot(ca.x < cpA)) + __popcll(__ballot(ca.y < cpA))
                 + __popcll(__ballot(ca.z < cpA)) + __popcll(__ballot(ca.w < cpA));
        int cntB = __popcll(__ballot(ca.x < cpB)) + __popcll(__ballot(ca.y < cpB))
                 + __popcll(__ballot(ca.z < cpB)) + __popcll(__ballot(ca.w < cpB));

        // row max: butterfly, two independent chains interleaved
        float mA = fmaxf(fmaxf(eA.x, eA.y), fmaxf(eA.z, eA.w));
        float mB = fmaxf(fmaxf(eB.x, eB.y), fmaxf(eB.z, eB.w));
        #pragma unroll
        for (int m = 32; m; m >>= 1) {
            mA = fmaxf(mA, __shfl_xor(mA, m, 64));
            mB = fmaxf(mB, __shfl_xor(mB, m, 64));
        }

        int iA = cntA < 1 ? 1 : (cntA > NC - 1 ? NC - 1 : cntA);
        int iB = cntB < 1 ? 1 : (cntB > NC - 1 ? NC - 1 : cntB);

        // e0/e1 fetched from registers by shuffle (idx is wave-uniform)
        int a0 = iA - 1, a1 = iA, b0 = iB - 1, b1 = iB;
        float sA0 = ((a0 & 3) == 0) ? eA.x : ((a0 & 3) == 1) ? eA.y : ((a0 & 3) == 2) ? eA.z : eA.w;
        float sA1 = ((a1 & 3) == 0) ? eA.x : ((a1 & 3) == 1) ? eA.y : ((a1 & 3) == 2) ? eA.z : eA.w;
        float sB0 = ((b0 & 3) == 0) ? eB.x : ((b0 & 3) == 1) ? eB.y : ((b0 & 3) == 2) ? eB.z : eB.w;
        float sB1 = ((b1 & 3) == 0) ? eB.x : ((b1 & 3) == 1) ? eB.y : ((b1 & 3) == 2) ? eB.z : eB.w;
        float e0A = __shfl(sA0, a0 >> 2, 64), e1A = __shfl(sA1, a1 >> 2, 64);
        float e0B = __shfl(sB0, b0 >> 2, 64), e1B = __shfl(sB1, b1 >> 2, 64);

        float c0A = csh[a0], c1A = csh[a1];
        float c0B = csh[b0], c1B = csh[b1];
        float wA = (cpA - c0A) / (c1A - c0A + 1e-12f);
        float wB = (cpB - c0B) / (c1B - c0B + 1e-12f);
        float eiA = fmaf(wA, e1A - e0A, e0A);
        float eiB = fmaf(wB, e1B - e0B, e0B);
        local += mA - eiA;
        local += has1 ? (mB - eiB) : 0.f;
    }
    // every lane holds the identical wave-uniform sum
    if (lane == 0) red[wv] = local;
    __syncthreads();
    if (tid == 0)
        atomicAdd(&bins[blockIdx.x & (NBINS - 1)], red[0] + red[1] + red[2] + red[3]);
}

// ---------------- K4: final reduce of bins -> out ----------------
__global__ __launch_bounds__(256) void k4_final(const float* __restrict__ bins,
                                                float* __restrict__ out) {
    __shared__ float red[4];
    int tid = threadIdx.x;
    float s = 0.f;
    for (int i = tid; i < NBINS; i += 256) s += bins[i];
    #pragma unroll
    for (int m = 32; m; m >>= 1) s += __shfl_xor(s, m, 64);
    int lane = tid & 63, wv = tid >> 6;
    if (lane == 0) red[wv] = s;
    __syncthreads();
    if (tid == 0) out[0] = -(red[0] + red[1] + red[2] + red[3]);  // / SIGMA^2 == 1
}

extern "C" void kernel_launch(void* const* d_in, const int* in_sizes, int n_in,
                              void* d_out, int out_size, void* d_ws, size_t ws_size,
                              hipStream_t stream) {
    const float* Vs      = (const float*)d_in[0];
    const float* A       = (const float*)d_in[1];
    const float* energy  = (const float*)d_in[2];
    const float* c_axis  = (const float*)d_in[3];
    const float* thick   = (const float*)d_in[4];
    const float* periods = (const float*)d_in[5];
    float* out = (float*)d_out;

    float* ws      = (float*)d_ws;
    float* r_pad   = ws;                                        // 2 MB
    float* partial = r_pad + (size_t)NGRID * PP;                // 16*4096*50*4 = 13.1 MB
    float* cpred   = partial + (size_t)NSPLIT * NOBS * NPERIODS;// 1 MB
    float* bins    = cpred + (size_t)NOBS * PP;                 // 4 KB

    hipLaunchKernelGGL(k1_rpad, dim3((NGRID * 64) / 256), dim3(256), 0, stream,
                       Vs, thick, periods, r_pad, bins);
    hipLaunchKernelGGL(k2_gemm, dim3(NOBS / OTILE, NSPLIT), dim3(256), 0, stream,
                       A, r_pad, partial);
    hipLaunchKernelGGL(k2b_reduce, dim3((NOBS * 64) / 256), dim3(256), 0, stream,
                       partial, cpred);
    hipLaunchKernelGGL(k3_main, dim3(NOBS), dim3(256), 0, stream,
                       energy, c_axis, cpred, bins);
    hipLaunchKernelGGL(k4_final, dim3(1), dim3(256), 0, stream, bins, out);
}